// Round 4
// baseline (235.143 us; speedup 1.0000x reference)
//
#include <hip/hip_runtime.h>

// MHA: B=4, S=2048, D=1024, H=16, Hd=64, causal. fp32 in/out, bf16 MFMA compute.
// cast -> fused QKV gemm (Q scaled, K row-major, V transposed) -> flash attn
// (32x32x16 MFMA, K+V^T double-buffered LDS w/ 1 barrier/iter, P exchanged via
// shfl_xor(32) in registers; T5 setprio on MFMA clusters) -> out gemm.
// GEMMs use the 128x128 m97-structure with 32x32x16 MFMA (2382 vs 2075 TF ubench;
// half the MFMA instruction count per K-tile at equal ds_read count).
// History: 256x256 8-phase port measured SLOWER twice (76 vs 66 us) — abandoned.

typedef float f32x4 __attribute__((ext_vector_type(4)));
typedef float f32x16 __attribute__((ext_vector_type(16)));
typedef short s16x8 __attribute__((ext_vector_type(8)));

#if __has_builtin(__builtin_amdgcn_exp2f)
#define EXP2(x) __builtin_amdgcn_exp2f(x)
#else
#define EXP2(x) exp2f(x)
#endif

// RNE float -> bf16 bits
__device__ __forceinline__ unsigned short f2bf(float f) {
  unsigned int u = __float_as_uint(f);
  u += 0x7fffu + ((u >> 16) & 1u);
  return (unsigned short)(u >> 16);
}

// pack two floats to bf16 pair, round-half-up
__device__ __forceinline__ unsigned int pk2bf(float f0, float f1) {
  return __builtin_amdgcn_perm(__float_as_uint(f1) + 0x8000u,
                               __float_as_uint(f0) + 0x8000u, 0x07060302u);
}

// pack two floats to bf16 pair, TRUNCATING (1 v_perm) — for P only
__device__ __forceinline__ unsigned int pk2bf_t(float f0, float f1) {
  return __builtin_amdgcn_perm(__float_as_uint(f1), __float_as_uint(f0), 0x07060302u);
}

// async global->LDS, 16 bytes per lane (wave-uniform LDS base + lane*16)
__device__ __forceinline__ void gl_lds16(const short* g, short* lds) {
  __builtin_amdgcn_global_load_lds(
      (const __attribute__((address_space(1))) unsigned int*)g,
      (__attribute__((address_space(3))) unsigned int*)lds, 16, 0, 0);
}

// ---------------- fp32 -> bf16 cast: X + all 4 weights, one dispatch ----------------
__global__ __launch_bounds__(256) void cvt_all(const float4* __restrict__ X,
                                               const float4* __restrict__ Wq,
                                               const float4* __restrict__ Wk,
                                               const float4* __restrict__ Wv,
                                               const float4* __restrict__ Wo,
                                               ushort4* __restrict__ xb,
                                               ushort4* __restrict__ wqkv,
                                               ushort4* __restrict__ wob) {
  const int NX = 8192 * 1024 / 4;
  const int NW = 1024 * 1024 / 4;
  const int NT = NX + 4 * NW;
  int i = blockIdx.x * blockDim.x + threadIdx.x;
  int stride = gridDim.x * blockDim.x;
  for (int idx = i; idx < NT; idx += stride) {
    const float4* s;
    ushort4* d;
    int off;
    if (idx < NX) {
      s = X; d = xb; off = idx;
    } else {
      int j = idx - NX;
      int w = j >> 18;
      off = j & (NW - 1);
      switch (w) {
        case 0: s = Wq; d = wqkv; break;
        case 1: s = Wk; d = wqkv + NW; break;
        case 2: s = Wv; d = wqkv + 2 * NW; break;
        default: s = Wo; d = wob; break;
      }
    }
    float4 f = s[off];
    ushort4 r;
    r.x = f2bf(f.x); r.y = f2bf(f.y); r.z = f2bf(f.z); r.w = f2bf(f.w);
    d[off] = r;
  }
}

// ---------------- GEMM: C[M,N] = A[M,K] * B[N,K]^T (both bf16 row-major) ----------------
// 32x32x16 MFMA. Per wave: 64x64 out = 2x2 tiles of 32x32, acc f32x16 each.
// C-layout (verified on-chip by attn's mask indexing): col = lane&31,
// row = (e&3) + 8*(e>>2) + 4*(lane>>5), e in [0,16).
// A/B frag: lane reads row (lane&31), k = kstep*16 + (lane>>5)*8 + j (ds_read_b128).
// MODE 0: fp32 output to Cf.
// MODE 1: QKV mode, N=3072: cols [0,1024) -> q_o (scaled bf16), [1024,2048) -> k_o,
//         [2048,3072) -> vT_o transposed as (b,h,d,s) with packed 8B stores.
template <int MODE>
__global__ __launch_bounds__(256) void gemm_bt(const short* __restrict__ A,
                                               const short* __restrict__ B,
                                               float* __restrict__ Cf,
                                               short* __restrict__ q_o,
                                               short* __restrict__ k_o,
                                               short* __restrict__ vT_o,
                                               int M, int N, int K) {
  const int tid = threadIdx.x;
  const int wave = tid >> 6, lane = tid & 63;
  const int l31 = lane & 31, h = lane >> 5;
  const int m0 = blockIdx.x * 128, n0 = blockIdx.y * 128;
  const int wm = (wave >> 1) * 64, wn = (wave & 1) * 64;

  __shared__ __align__(16) short As[128 * 64];
  __shared__ __align__(16) short Bs[128 * 64];

  f32x16 acc[2][2];
#pragma unroll
  for (int i = 0; i < 2; ++i)
#pragma unroll
    for (int j = 0; j < 2; ++j)
#pragma unroll
      for (int e = 0; e < 16; ++e) acc[i][j][e] = 0.f;

  for (int k0 = 0; k0 < K; k0 += 64) {
    __syncthreads();
    for (int i = 0; i < 4; ++i) {
      int c = wave * 4 + i;
      int r = c * 8 + (lane >> 3);
      int c8 = (lane & 7) ^ (r & 7);
      gl_lds16(A + (size_t)(m0 + r) * K + k0 + c8 * 8, As + c * 512 + lane * 8);
      gl_lds16(B + (size_t)(n0 + r) * K + k0 + c8 * 8, Bs + c * 512 + lane * 8);
    }
    __syncthreads();
#pragma unroll
    for (int half = 0; half < 2; ++half) {
      // ksteps 2*half, 2*half+1; 8-elem group index g8 = kstep*2 + h
      s16x8 af[2][2], bfr[2][2];
#pragma unroll
      for (int mt = 0; mt < 2; ++mt) {
        int row = wm + mt * 32 + l31;
#pragma unroll
        for (int j = 0; j < 2; ++j) {
          int g8 = half * 4 + j * 2 + h;
          af[mt][j] = *(const s16x8*)(As + row * 64 + ((g8 ^ (row & 7)) << 3));
        }
      }
#pragma unroll
      for (int nt = 0; nt < 2; ++nt) {
        int row = wn + nt * 32 + l31;
#pragma unroll
        for (int j = 0; j < 2; ++j) {
          int g8 = half * 4 + j * 2 + h;
          bfr[nt][j] = *(const s16x8*)(Bs + row * 64 + ((g8 ^ (row & 7)) << 3));
        }
      }
#pragma unroll
      for (int mt = 0; mt < 2; ++mt)
#pragma unroll
        for (int nt = 0; nt < 2; ++nt)
#pragma unroll
          for (int j = 0; j < 2; ++j)
            acc[mt][nt] = __builtin_amdgcn_mfma_f32_32x32x16_bf16(af[mt][j], bfr[nt][j],
                                                                  acc[mt][nt], 0, 0, 0);
    }
  }

  if (MODE == 0) {
#pragma unroll
    for (int mt = 0; mt < 2; ++mt)
#pragma unroll
      for (int nt = 0; nt < 2; ++nt) {
        int col = n0 + wn + nt * 32 + l31;
#pragma unroll
        for (int e = 0; e < 16; ++e) {
          int row = m0 + wm + mt * 32 + (e & 3) + 8 * (e >> 2) + 4 * h;
          Cf[(size_t)row * N + col] = acc[mt][nt][e];
        }
      }
  } else {
    if (n0 < 1024) {  // Q, fold softmax scale * log2(e)
      const float scale = 0.18033688011112042f;  // 0.125 * log2(e)
#pragma unroll
      for (int mt = 0; mt < 2; ++mt)
#pragma unroll
        for (int nt = 0; nt < 2; ++nt) {
          int col = n0 + wn + nt * 32 + l31;
#pragma unroll
          for (int e = 0; e < 16; ++e) {
            int row = m0 + wm + mt * 32 + (e & 3) + 8 * (e >> 2) + 4 * h;
            ((unsigned short*)q_o)[(size_t)row * 1024 + col] = f2bf(acc[mt][nt][e] * scale);
          }
        }
    } else if (n0 < 2048) {  // K
#pragma unroll
      for (int mt = 0; mt < 2; ++mt)
#pragma unroll
        for (int nt = 0; nt < 2; ++nt) {
          int col = n0 - 1024 + wn + nt * 32 + l31;
#pragma unroll
          for (int e = 0; e < 16; ++e) {
            int row = m0 + wm + mt * 32 + (e & 3) + 8 * (e >> 2) + 4 * h;
            ((unsigned short*)k_o)[(size_t)row * 1024 + col] = f2bf(acc[mt][nt][e]);
          }
        }
    } else {  // V transposed: vT[((b*16+h)*64+d)*2048 + s], 4 consecutive s per lane
#pragma unroll
      for (int mt = 0; mt < 2; ++mt)
#pragma unroll
        for (int nt = 0; nt < 2; ++nt) {
          int col = n0 - 2048 + wn + nt * 32 + l31;
          int hh = col >> 6, d = col & 63;
#pragma unroll
          for (int g = 0; g < 4; ++g) {
            int row0 = m0 + wm + mt * 32 + 8 * g + 4 * h;
            int b = row0 >> 11, s = row0 & 2047;
            uint2 pk;
            pk.x = pk2bf(acc[mt][nt][4 * g + 0], acc[mt][nt][4 * g + 1]);
            pk.y = pk2bf(acc[mt][nt][4 * g + 2], acc[mt][nt][4 * g + 3]);
            *(uint2*)((unsigned short*)vT_o + (((size_t)b * 16 + hh) * 64 + d) * 2048 + s) = pk;
          }
        }
    }
  }
}

// ---------------- flash attention: 32x32 MFMA, dbuf staging, register-P ----------------
// grid (64 bh, 16 y): qt = 15 - y (heavy blocks dispatch first). 4 waves x 32 q each.
// Lane holds ONE q column (l31) in S^T C-layout -> softmax per-lane, l reduced with a
// single shfl_xor(32). P^T B-frags for PV built from registers with one uint2
// shfl_xor(32) exchange per 16-kv step. K/V^T double-buffered: DMA for t+1 issued
// right after the single per-iter barrier -> full iteration to complete (no drain).
// T5: s_setprio(1) around the QK^T and PV MFMA clusters (R3: −4.3 us total, kept).
__global__ __launch_bounds__(256, 2) void attn_kernel(const short* __restrict__ qb,
                                                      const short* __restrict__ kb,
                                                      const short* __restrict__ vT,
                                                      short* __restrict__ ob) {
  const int bh = blockIdx.x;
  const int qt = 15 - (int)blockIdx.y;
  const int tid = threadIdx.x;
  const int wave = tid >> 6, lane = tid & 63;
  const int l31 = lane & 31, h = lane >> 5;
  const int q0 = qt * 128;
  const size_t rowbase = (size_t)(bh >> 4) * 2048;
  const int hoff = (bh & 15) * 64;

  __shared__ __align__(16) short Ks[2][8192];   // 128 kv x 64 d, swizzled (32 KB)
  __shared__ __align__(16) short VTs[2][8192];  // 64 d x 128 kv, swizzled (32 KB)

  // staging coords: chunks c = wave*4+i, 512 shorts each
  const int kc = wave * 4;
  const int kr = kc * 8 + (lane >> 3);            // K row (8 rows per chunk)
  const short* ksrc = kb + (rowbase + kr) * 1024 + hoff + (((lane & 7) ^ (kr & 7)) << 3);
  const int vg = lane & 15;
  const short* vsrc_i[4];
#pragma unroll
  for (int i = 0; i < 4; ++i) {
    int d = (kc + i) * 4 + (lane >> 4);           // V^T d-row (4 rows per chunk)
    vsrc_i[i] = vT + ((size_t)bh * 64 + d) * 2048 + ((vg ^ (d & 7)) << 3);
  }

  // Q B-frags: lane(q=l31, d = ks*16 + h*8 + j)
  s16x8 qf[4];
  {
    const short* qrow = qb + (rowbase + q0 + wave * 32 + l31) * 1024 + hoff + h * 8;
#pragma unroll
    for (int k = 0; k < 4; ++k) qf[k] = *(const s16x8*)(qrow + k * 16);
  }

  // prologue: stage t=0 into buffer 0
#pragma unroll
  for (int i = 0; i < 4; ++i)
    gl_lds16(ksrc + i * 8 * 1024, Ks[0] + (kc + i) * 512 + lane * 8);
#pragma unroll
  for (int i = 0; i < 4; ++i)
    gl_lds16(vsrc_i[i], VTs[0] + (kc + i) * 512 + lane * 8);

  f32x16 oacc[2];  // O^T: [d-tile], col=q=l31, row_d=(e&3)+8*(e>>2)+4h+32dt
#pragma unroll
  for (int dt = 0; dt < 2; ++dt)
#pragma unroll
    for (int e = 0; e < 16; ++e) oacc[dt][e] = 0.f;
  float lacc = 0.f;
  const int kswz = l31 & 7;

  for (int t = 0; t <= qt; ++t) {
    __syncthreads();  // drains DMA(t) (issued a full iter ago); LDS reads of old buf done
    const int cur = t & 1;

    if (t < qt) {  // stage t+1 into alternate buffers; whole iteration to complete
      const int nxt = cur ^ 1;
      const short* ks = ksrc + (size_t)(t + 1) * 128 * 1024;
#pragma unroll
      for (int i = 0; i < 4; ++i)
        gl_lds16(ks + i * 8 * 1024, Ks[nxt] + (kc + i) * 512 + lane * 8);
#pragma unroll
      for (int i = 0; i < 4; ++i)
        gl_lds16(vsrc_i[i] + (t + 1) * 128, VTs[nxt] + (kc + i) * 512 + lane * 8);
    }

    const short* Kc = Ks[cur];
    const short* Vc = VTs[cur];

    // S^T = K * Q^T, 4 m-tiles of 32 kv, computed in 2 groups to bound registers.
    // C-layout: col=q=l31, row_kv=(e&3)+8*(e>>2)+4h (+32m). Then exp2 + pack to pp.
    unsigned int pp[4][8];  // P bf16 pairs: pp[m][rg] = (reg 2rg, reg 2rg+1)
    float sum = 0.f;
#pragma unroll
    for (int g = 0; g < 2; ++g) {
      f32x16 s0, s1;
#pragma unroll
      for (int e = 0; e < 16; ++e) { s0[e] = 0.f; s1[e] = 0.f; }
      __builtin_amdgcn_s_setprio(1);
#pragma unroll
      for (int ks = 0; ks < 4; ++ks) {
        int pos = ((ks << 1) + h) ^ kswz;
        s16x8 kf0 = *(const s16x8*)(Kc + ((2 * g) * 32 + l31) * 64 + (pos << 3));
        s16x8 kf1 = *(const s16x8*)(Kc + ((2 * g + 1) * 32 + l31) * 64 + (pos << 3));
        s0 = __builtin_amdgcn_mfma_f32_32x32x16_bf16(kf0, qf[ks], s0, 0, 0, 0);
        s1 = __builtin_amdgcn_mfma_f32_32x32x16_bf16(kf1, qf[ks], s1, 0, 0, 0);
      }
      __builtin_amdgcn_s_setprio(0);
      if (t == qt) {  // causal mask on diagonal tile (local compare: t*128 == q0)
        int qg = wave * 32 + l31;
#pragma unroll
        for (int e = 0; e < 16; ++e) {
          int rloc = (e & 3) + 8 * (e >> 2) + 4 * h;
          if ((2 * g) * 32 + rloc > qg) s0[e] = -1e30f;
          if ((2 * g + 1) * 32 + rloc > qg) s1[e] = -1e30f;
        }
      }
#pragma unroll
      for (int rg = 0; rg < 8; ++rg) {
        float a0 = EXP2(s0[2 * rg]), a1 = EXP2(s0[2 * rg + 1]);
        float b0 = EXP2(s1[2 * rg]), b1 = EXP2(s1[2 * rg + 1]);
        sum += (a0 + a1) + (b0 + b1);
        pp[2 * g][rg] = pk2bf_t(a0, a1);
        pp[2 * g + 1][rg] = pk2bf_t(b0, b1);
      }
    }
    lacc += sum;

    // O^T += V^T * P^T. B-frag(kv step s): lane(q=l31, kv=s*16+h*8+j).
    // Rows 4h-interleave -> one uint2 shfl_xor(32) exchange + selects per step.
#pragma unroll
    for (int s = 0; s < 8; ++s) {
      int m = s >> 1, base = (s & 1) * 4;
      unsigned int ax = pp[m][base + 0], ay = pp[m][base + 1];
      unsigned int bx = pp[m][base + 2], by = pp[m][base + 3];
      unsigned int sx = h ? ax : bx, sy = h ? ay : by;
      unsigned int rx = (unsigned int)__shfl_xor((int)sx, 32);
      unsigned int ry = (unsigned int)__shfl_xor((int)sy, 32);
      union { s16x8 v; unsigned int u[4]; } pf;
      pf.u[0] = h ? rx : ax;
      pf.u[1] = h ? ry : ay;
      pf.u[2] = h ? bx : rx;
      pf.u[3] = h ? by : ry;
      __builtin_amdgcn_s_setprio(1);
#pragma unroll
      for (int dt = 0; dt < 2; ++dt) {
        int d = dt * 32 + l31;
        s16x8 vf = *(const s16x8*)(Vc + d * 128 + ((((s << 1) + h) ^ (d & 7)) << 3));
        oacc[dt] = __builtin_amdgcn_mfma_f32_32x32x16_bf16(vf, pf.v, oacc[dt], 0, 0, 0);
      }
      __builtin_amdgcn_s_setprio(0);
    }
  }

  // epilogue: l across the two half-lanes, normalize, store O rows (8B stores)
  lacc += __shfl_xor(lacc, 32);
  float inv = 1.0f / lacc;
  size_t row = rowbase + q0 + wave * 32 + l31;
  unsigned short* orow = (unsigned short*)ob + row * 1024 + hoff;
#pragma unroll
  for (int dt = 0; dt < 2; ++dt)
#pragma unroll
    for (int rg = 0; rg < 4; ++rg) {
      int d = dt * 32 + rg * 8 + 4 * h;
      uint2 pk;
      pk.x = pk2bf(oacc[dt][rg * 4 + 0] * inv, oacc[dt][rg * 4 + 1] * inv);
      pk.y = pk2bf(oacc[dt][rg * 4 + 2] * inv, oacc[dt][rg * 4 + 3] * inv);
      *(uint2*)(orow + d) = pk;
    }
}

extern "C" void kernel_launch(void* const* d_in, const int* in_sizes, int n_in,
                              void* d_out, int out_size, void* d_ws, size_t ws_size,
                              hipStream_t stream) {
  const float* X  = (const float*)d_in[0];
  const float* Wq = (const float*)d_in[1];
  const float* Wk = (const float*)d_in[2];
  const float* Wv = (const float*)d_in[3];
  const float* Wo = (const float*)d_in[4];

  // workspace (bf16 shorts), 72 MB total; ob aliases xb (dead after QKV gemm)
  short* xb   = (short*)d_ws;                    // 8192x1024 (16 MB)
  short* wqkv = xb + (size_t)8192 * 1024;        // 3072x1024 ( 6 MB)
  short* wob  = wqkv + (size_t)3072 * 1024;      // 1024x1024 ( 2 MB)
  short* qb   = wob + (size_t)1024 * 1024;       // 8192x1024 (16 MB)
  short* kb   = qb + (size_t)8192 * 1024;        // 8192x1024 (16 MB)
  short* vT   = kb + (size_t)8192 * 1024;        // (4,16,64,2048) (16 MB)
  short* ob   = xb;

  const int MB = 8192;

  cvt_all<<<3072, 256, 0, stream>>>((const float4*)X, (const float4*)Wq, (const float4*)Wk,
                                    (const float4*)Wv, (const float4*)Wo, (ushort4*)xb,
                                    (ushort4*)wqkv, (ushort4*)wob);

  // fused QKV projection -> qb (scaled), kb, vT
  gemm_bt<1><<<dim3(64, 24), 256, 0, stream>>>(xb, wqkv, nullptr, qb, kb, vT, MB, 3072, 1024);

  // flash attention -> ob (bf16)
  attn_kernel<<<dim3(64, 16), 256, 0, stream>>>(qb, kb, vT, ob);

  // output projection -> fp32 d_out
  gemm_bt<0><<<dim3(64, 8), 256, 0, stream>>>(ob, wob, (float*)d_out, nullptr, nullptr,
                                              nullptr, MB, 1024, 1024);
}

// Round 6
// 228.197 us; speedup vs baseline: 1.0304x; 1.0304x over previous
//
#include <hip/hip_runtime.h>

// MHA: B=4, S=2048, D=1024, H=16, Hd=64, causal. fp32 in/out, bf16 MFMA compute.
// cast -> fused QKV gemm (Q scaled, K row-major, V transposed) -> flash attn
// (32x32x16 MFMA, K+V^T double-buffered LDS w/ 1 barrier/iter, P exchanged via
// v_permlane32_swap in registers; T5 setprio on MFMA clusters) -> out gemm.
// GEMMs: 128x128 m97-structure, 16x16x32 MFMA. History: 256x256 8-phase port
// slower twice (76 vs 66 us); 32x32x16 GEMM frags slower (75.5 us — structural
// 4-way LDS read conflict); permlane32_swap with D.lo<->S.hi assumption FAILED
// correctness (R5) -> convention is D.hi<->S.lo ("odd half of VDST with even
// half of SRC0", per the permlane16_swap row pattern). Operands flipped here.

typedef float f32x4 __attribute__((ext_vector_type(4)));
typedef float f32x16 __attribute__((ext_vector_type(16)));
typedef short s16x8 __attribute__((ext_vector_type(8)));

#if __has_builtin(__builtin_amdgcn_exp2f)
#define EXP2(x) __builtin_amdgcn_exp2f(x)
#else
#define EXP2(x) exp2f(x)
#endif

// RNE float -> bf16 bits
__device__ __forceinline__ unsigned short f2bf(float f) {
  unsigned int u = __float_as_uint(f);
  u += 0x7fffu + ((u >> 16) & 1u);
  return (unsigned short)(u >> 16);
}

// pack two floats to bf16 pair, round-half-up
__device__ __forceinline__ unsigned int pk2bf(float f0, float f1) {
  return __builtin_amdgcn_perm(__float_as_uint(f1) + 0x8000u,
                               __float_as_uint(f0) + 0x8000u, 0x07060302u);
}

// pack two floats to bf16 pair, TRUNCATING (1 v_perm) — for P only
__device__ __forceinline__ unsigned int pk2bf_t(float f0, float f1) {
  return __builtin_amdgcn_perm(__float_as_uint(f1), __float_as_uint(f0), 0x07060302u);
}

// async global->LDS, 16 bytes per lane (wave-uniform LDS base + lane*16)
__device__ __forceinline__ void gl_lds16(const short* g, short* lds) {
  __builtin_amdgcn_global_load_lds(
      (const __attribute__((address_space(1))) unsigned int*)g,
      (__attribute__((address_space(3))) unsigned int*)lds, 16, 0, 0);
}

// ---------------- fp32 -> bf16 cast: X + all 4 weights, one dispatch ----------------
__global__ __launch_bounds__(256) void cvt_all(const float4* __restrict__ X,
                                               const float4* __restrict__ Wq,
                                               const float4* __restrict__ Wk,
                                               const float4* __restrict__ Wv,
                                               const float4* __restrict__ Wo,
                                               ushort4* __restrict__ xb,
                                               ushort4* __restrict__ wqkv,
                                               ushort4* __restrict__ wob) {
  const int NX = 8192 * 1024 / 4;
  const int NW = 1024 * 1024 / 4;
  const int NT = NX + 4 * NW;
  int i = blockIdx.x * blockDim.x + threadIdx.x;
  int stride = gridDim.x * blockDim.x;
  for (int idx = i; idx < NT; idx += stride) {
    const float4* s;
    ushort4* d;
    int off;
    if (idx < NX) {
      s = X; d = xb; off = idx;
    } else {
      int j = idx - NX;
      int w = j >> 18;
      off = j & (NW - 1);
      switch (w) {
        case 0: s = Wq; d = wqkv; break;
        case 1: s = Wk; d = wqkv + NW; break;
        case 2: s = Wv; d = wqkv + 2 * NW; break;
        default: s = Wo; d = wob; break;
      }
    }
    float4 f = s[off];
    ushort4 r;
    r.x = f2bf(f.x); r.y = f2bf(f.y); r.z = f2bf(f.z); r.w = f2bf(f.w);
    d[off] = r;
  }
}

// ---------------- GEMM: C[M,N] = A[M,K] * B[N,K]^T (both bf16 row-major) ----------------
// MODE 0: fp32 output to Cf.
// MODE 1: QKV mode, N=3072: cols [0,1024) -> q_o (scaled bf16), [1024,2048) -> k_o,
//         [2048,3072) -> vT_o transposed as (b,h,d,s) with packed 8B stores.
template <int MODE>
__global__ __launch_bounds__(256) void gemm_bt(const short* __restrict__ A,
                                               const short* __restrict__ B,
                                               float* __restrict__ Cf,
                                               short* __restrict__ q_o,
                                               short* __restrict__ k_o,
                                               short* __restrict__ vT_o,
                                               int M, int N, int K) {
  const int tid = threadIdx.x;
  const int wave = tid >> 6, lane = tid & 63;
  const int quad = lane >> 4, l15 = lane & 15;
  const int m0 = blockIdx.x * 128, n0 = blockIdx.y * 128;
  const int wm = (wave >> 1) * 64, wn = (wave & 1) * 64;

  __shared__ __align__(16) short As[128 * 64];
  __shared__ __align__(16) short Bs[128 * 64];

  const f32x4 z4 = {0.f, 0.f, 0.f, 0.f};
  f32x4 acc[4][4];
  for (int i = 0; i < 4; ++i)
    for (int j = 0; j < 4; ++j) acc[i][j] = z4;

  for (int k0 = 0; k0 < K; k0 += 64) {
    __syncthreads();
    for (int i = 0; i < 4; ++i) {
      int c = wave * 4 + i;
      int r = c * 8 + (lane >> 3);
      int c8 = (lane & 7) ^ (r & 7);
      gl_lds16(A + (size_t)(m0 + r) * K + k0 + c8 * 8, As + c * 512 + lane * 8);
      gl_lds16(B + (size_t)(n0 + r) * K + k0 + c8 * 8, Bs + c * 512 + lane * 8);
    }
    __syncthreads();
    for (int kk = 0; kk < 64; kk += 32) {
      int c8b = (kk >> 3) + quad;
      s16x8 af[4], bfr[4];
      for (int mt = 0; mt < 4; ++mt) {
        int row = wm + mt * 16 + l15;
        af[mt] = *(const s16x8*)(As + row * 64 + ((c8b ^ (row & 7)) << 3));
      }
      for (int nt = 0; nt < 4; ++nt) {
        int row = wn + nt * 16 + l15;
        bfr[nt] = *(const s16x8*)(Bs + row * 64 + ((c8b ^ (row & 7)) << 3));
      }
      for (int mt = 0; mt < 4; ++mt)
        for (int nt = 0; nt < 4; ++nt)
          acc[mt][nt] = __builtin_amdgcn_mfma_f32_16x16x32_bf16(af[mt], bfr[nt],
                                                                acc[mt][nt], 0, 0, 0);
    }
  }

  if (MODE == 0) {
    for (int mt = 0; mt < 4; ++mt)
      for (int nt = 0; nt < 4; ++nt) {
        int col = n0 + wn + nt * 16 + l15;
        for (int r = 0; r < 4; ++r) {
          int row = m0 + wm + mt * 16 + quad * 4 + r;
          Cf[(size_t)row * N + col] = acc[mt][nt][r];
        }
      }
  } else {
    if (n0 < 1024) {  // Q, fold softmax scale * log2(e)
      const float scale = 0.18033688011112042f;  // 0.125 * log2(e)
      for (int mt = 0; mt < 4; ++mt)
        for (int nt = 0; nt < 4; ++nt) {
          int col = n0 + wn + nt * 16 + l15;
          for (int r = 0; r < 4; ++r) {
            int row = m0 + wm + mt * 16 + quad * 4 + r;
            ((unsigned short*)q_o)[(size_t)row * 1024 + col] = f2bf(acc[mt][nt][r] * scale);
          }
        }
    } else if (n0 < 2048) {  // K
      for (int mt = 0; mt < 4; ++mt)
        for (int nt = 0; nt < 4; ++nt) {
          int col = n0 - 1024 + wn + nt * 16 + l15;
          for (int r = 0; r < 4; ++r) {
            int row = m0 + wm + mt * 16 + quad * 4 + r;
            ((unsigned short*)k_o)[(size_t)row * 1024 + col] = f2bf(acc[mt][nt][r]);
          }
        }
    } else {  // V transposed: vT[((b*16+h)*64+d)*2048 + s], 4 consecutive s per lane
      for (int mt = 0; mt < 4; ++mt)
        for (int nt = 0; nt < 4; ++nt) {
          int col = n0 - 2048 + wn + nt * 16 + l15;
          int h = col >> 6, d = col & 63;
          int row0 = m0 + wm + mt * 16 + quad * 4;
          int b = row0 >> 11, s = row0 & 2047;
          uint2 pk;
          pk.x = pk2bf(acc[mt][nt][0], acc[mt][nt][1]);
          pk.y = pk2bf(acc[mt][nt][2], acc[mt][nt][3]);
          *(uint2*)((unsigned short*)vT_o + (((size_t)b * 16 + h) * 64 + d) * 2048 + s) = pk;
        }
    }
  }
}

// ---------------- flash attention: 32x32 MFMA, dbuf staging, register-P ----------------
// grid (64 bh, 16 y): qt = 15 - y (heavy blocks dispatch first). 4 waves x 32 q each.
// Lane holds ONE q column (l31) in S^T C-layout -> softmax per-lane, l reduced with a
// single shfl_xor(32). P^T B-frags for PV built from registers; the half-wave
// exchange per 16-kv step is ONE v_permlane32_swap_b32 pair (D.hi <-> S.lo):
//   swap(D=cax, S=cbx):  cax = {ax.lo | bx[lane-32] in hi} = pf.u[0]
//                        cbx = {ax[lane+32] in lo | bx.hi} = pf.u[2]
// replacing 2 selects + 2 shfl_xor(LDS pipe) + 4 selects (exact equivalence).
// K/V^T double-buffered: DMA for t+1 issued right after the single per-iter barrier.
// T5: s_setprio(1) around the QK^T and PV MFMA clusters (R3: −4.3 us total, kept).
__global__ __launch_bounds__(256, 2) void attn_kernel(const short* __restrict__ qb,
                                                      const short* __restrict__ kb,
                                                      const short* __restrict__ vT,
                                                      short* __restrict__ ob) {
  const int bh = blockIdx.x;
  const int qt = 15 - (int)blockIdx.y;
  const int tid = threadIdx.x;
  const int wave = tid >> 6, lane = tid & 63;
  const int l31 = lane & 31, h = lane >> 5;
  const int q0 = qt * 128;
  const size_t rowbase = (size_t)(bh >> 4) * 2048;
  const int hoff = (bh & 15) * 64;

  __shared__ __align__(16) short Ks[2][8192];   // 128 kv x 64 d, swizzled (32 KB)
  __shared__ __align__(16) short VTs[2][8192];  // 64 d x 128 kv, swizzled (32 KB)

  // staging coords: chunks c = wave*4+i, 512 shorts each
  const int kc = wave * 4;
  const int kr = kc * 8 + (lane >> 3);            // K row (8 rows per chunk)
  const short* ksrc = kb + (rowbase + kr) * 1024 + hoff + (((lane & 7) ^ (kr & 7)) << 3);
  const int vg = lane & 15;
  const short* vsrc_i[4];
#pragma unroll
  for (int i = 0; i < 4; ++i) {
    int d = (kc + i) * 4 + (lane >> 4);           // V^T d-row (4 rows per chunk)
    vsrc_i[i] = vT + ((size_t)bh * 64 + d) * 2048 + ((vg ^ (d & 7)) << 3);
  }

  // Q B-frags: lane(q=l31, d = ks*16 + h*8 + j)
  s16x8 qf[4];
  {
    const short* qrow = qb + (rowbase + q0 + wave * 32 + l31) * 1024 + hoff + h * 8;
#pragma unroll
    for (int k = 0; k < 4; ++k) qf[k] = *(const s16x8*)(qrow + k * 16);
  }

  // prologue: stage t=0 into buffer 0
#pragma unroll
  for (int i = 0; i < 4; ++i)
    gl_lds16(ksrc + i * 8 * 1024, Ks[0] + (kc + i) * 512 + lane * 8);
#pragma unroll
  for (int i = 0; i < 4; ++i)
    gl_lds16(vsrc_i[i], VTs[0] + (kc + i) * 512 + lane * 8);

  f32x16 oacc[2];  // O^T: [d-tile], col=q=l31, row_d=(e&3)+8*(e>>2)+4h+32dt
#pragma unroll
  for (int dt = 0; dt < 2; ++dt)
#pragma unroll
    for (int e = 0; e < 16; ++e) oacc[dt][e] = 0.f;
  float lacc = 0.f;
  const int kswz = l31 & 7;

  for (int t = 0; t <= qt; ++t) {
    __syncthreads();  // drains DMA(t) (issued a full iter ago); LDS reads of old buf done
    const int cur = t & 1;

    if (t < qt) {  // stage t+1 into alternate buffers; whole iteration to complete
      const int nxt = cur ^ 1;
      const short* ks = ksrc + (size_t)(t + 1) * 128 * 1024;
#pragma unroll
      for (int i = 0; i < 4; ++i)
        gl_lds16(ks + i * 8 * 1024, Ks[nxt] + (kc + i) * 512 + lane * 8);
#pragma unroll
      for (int i = 0; i < 4; ++i)
        gl_lds16(vsrc_i[i] + (t + 1) * 128, VTs[nxt] + (kc + i) * 512 + lane * 8);
    }

    const short* Kc = Ks[cur];
    const short* Vc = VTs[cur];

    // S^T = K * Q^T, 4 m-tiles of 32 kv, computed in 2 groups to bound registers.
    // C-layout: col=q=l31, row_kv=(e&3)+8*(e>>2)+4h (+32m). Then exp2 + pack to pp.
    unsigned int pp[4][8];  // P bf16 pairs: pp[m][rg] = (reg 2rg, reg 2rg+1)
    float sum = 0.f;
#pragma unroll
    for (int g = 0; g < 2; ++g) {
      f32x16 s0, s1;
#pragma unroll
      for (int e = 0; e < 16; ++e) { s0[e] = 0.f; s1[e] = 0.f; }
      __builtin_amdgcn_s_setprio(1);
#pragma unroll
      for (int ks = 0; ks < 4; ++ks) {
        int pos = ((ks << 1) + h) ^ kswz;
        s16x8 kf0 = *(const s16x8*)(Kc + ((2 * g) * 32 + l31) * 64 + (pos << 3));
        s16x8 kf1 = *(const s16x8*)(Kc + ((2 * g + 1) * 32 + l31) * 64 + (pos << 3));
        s0 = __builtin_amdgcn_mfma_f32_32x32x16_bf16(kf0, qf[ks], s0, 0, 0, 0);
        s1 = __builtin_amdgcn_mfma_f32_32x32x16_bf16(kf1, qf[ks], s1, 0, 0, 0);
      }
      __builtin_amdgcn_s_setprio(0);
      if (t == qt) {  // causal mask on diagonal tile (local compare: t*128 == q0)
        int qg = wave * 32 + l31;
#pragma unroll
        for (int e = 0; e < 16; ++e) {
          int rloc = (e & 3) + 8 * (e >> 2) + 4 * h;
          if ((2 * g) * 32 + rloc > qg) s0[e] = -1e30f;
          if ((2 * g + 1) * 32 + rloc > qg) s1[e] = -1e30f;
        }
      }
#pragma unroll
      for (int rg = 0; rg < 8; ++rg) {
        float a0 = EXP2(s0[2 * rg]), a1 = EXP2(s0[2 * rg + 1]);
        float b0 = EXP2(s1[2 * rg]), b1 = EXP2(s1[2 * rg + 1]);
        sum += (a0 + a1) + (b0 + b1);
        pp[2 * g][rg] = pk2bf_t(a0, a1);
        pp[2 * g + 1][rg] = pk2bf_t(b0, b1);
      }
    }
    lacc += sum;

    // O^T += V^T * P^T. B-frag(kv step s): lane(q=l31, kv=s*16+h*8+j).
    // Half-wave row interleave resolved with one permlane32_swap pair per step.
#pragma unroll
    for (int s = 0; s < 8; ++s) {
      int m = s >> 1, base = (s & 1) * 4;
      unsigned int cax = pp[m][base + 0], cay = pp[m][base + 1];
      unsigned int cbx = pp[m][base + 2], cby = pp[m][base + 3];
      // D.hi <-> S.lo:  cax := {ax.lo, bx.lo(hi-half)}, cbx := {ax.hi(lo-half), bx.hi}
      asm("v_permlane32_swap_b32 %0, %1" : "+v"(cax), "+v"(cbx));
      asm("v_permlane32_swap_b32 %0, %1" : "+v"(cay), "+v"(cby));
      union { s16x8 v; unsigned int u[4]; } pf;
      pf.u[0] = cax;
      pf.u[1] = cay;
      pf.u[2] = cbx;
      pf.u[3] = cby;
      __builtin_amdgcn_s_setprio(1);
#pragma unroll
      for (int dt = 0; dt < 2; ++dt) {
        int d = dt * 32 + l31;
        s16x8 vf = *(const s16x8*)(Vc + d * 128 + ((((s << 1) + h) ^ (d & 7)) << 3));
        oacc[dt] = __builtin_amdgcn_mfma_f32_32x32x16_bf16(vf, pf.v, oacc[dt], 0, 0, 0);
      }
      __builtin_amdgcn_s_setprio(0);
    }
  }

  // epilogue: l across the two half-lanes, normalize, store O rows (8B stores)
  lacc += __shfl_xor(lacc, 32);
  float inv = 1.0f / lacc;
  size_t row = rowbase + q0 + wave * 32 + l31;
  unsigned short* orow = (unsigned short*)ob + row * 1024 + hoff;
#pragma unroll
  for (int dt = 0; dt < 2; ++dt)
#pragma unroll
    for (int rg = 0; rg < 4; ++rg) {
      int d = dt * 32 + rg * 8 + 4 * h;
      uint2 pk;
      pk.x = pk2bf(oacc[dt][rg * 4 + 0] * inv, oacc[dt][rg * 4 + 1] * inv);
      pk.y = pk2bf(oacc[dt][rg * 4 + 2] * inv, oacc[dt][rg * 4 + 3] * inv);
      *(uint2*)(orow + d) = pk;
    }
}

extern "C" void kernel_launch(void* const* d_in, const int* in_sizes, int n_in,
                              void* d_out, int out_size, void* d_ws, size_t ws_size,
                              hipStream_t stream) {
  const float* X  = (const float*)d_in[0];
  const float* Wq = (const float*)d_in[1];
  const float* Wk = (const float*)d_in[2];
  const float* Wv = (const float*)d_in[3];
  const float* Wo = (const float*)d_in[4];

  // workspace (bf16 shorts), 72 MB total; ob aliases xb (dead after QKV gemm)
  short* xb   = (short*)d_ws;                    // 8192x1024 (16 MB)
  short* wqkv = xb + (size_t)8192 * 1024;        // 3072x1024 ( 6 MB)
  short* wob  = wqkv + (size_t)3072 * 1024;      // 1024x1024 ( 2 MB)
  short* qb   = wob + (size_t)1024 * 1024;       // 8192x1024 (16 MB)
  short* kb   = qb + (size_t)8192 * 1024;        // 8192x1024 (16 MB)
  short* vT   = kb + (size_t)8192 * 1024;        // (4,16,64,2048) (16 MB)
  short* ob   = xb;

  const int MB = 8192;

  cvt_all<<<3072, 256, 0, stream>>>((const float4*)X, (const float4*)Wq, (const float4*)Wk,
                                    (const float4*)Wv, (const float4*)Wo, (ushort4*)xb,
                                    (ushort4*)wqkv, (ushort4*)wob);

  // fused QKV projection -> qb (scaled), kb, vT
  gemm_bt<1><<<dim3(64, 24), 256, 0, stream>>>(xb, wqkv, nullptr, qb, kb, vT, MB, 3072, 1024);

  // flash attention -> ob (bf16)
  attn_kernel<<<dim3(64, 16), 256, 0, stream>>>(qb, kb, vT, ob);

  // output projection -> fp32 d_out
  gemm_bt<0><<<dim3(64, 8), 256, 0, stream>>>(ob, wob, (float*)d_out, nullptr, nullptr,
                                              nullptr, MB, 1024, 1024);
}